// Round 1
// baseline (6731.902 us; speedup 1.0000x reference)
//
#include <hip/hip_runtime.h>
#include <hip/hip_bf16.h>
#include <hip/hip_cooperative_groups.h>

namespace cg = cooperative_groups;

#define N_DIM 1024
#define R_DIM 6
#define B_DIM 64
#define T_DIM 400

typedef short bf16x8 __attribute__((ext_vector_type(8)));
typedef float f32x4 __attribute__((ext_vector_type(4)));

__device__ inline unsigned short f2bf(float f) {
    // round-to-nearest-even bf16 (finite inputs)
    unsigned int u = __float_as_uint(f);
    unsigned int r = (u + 0x7fffu + ((u >> 16) & 1u)) >> 16;
    return (unsigned short)r;
}

// Build W in MFMA B-fragment layout, bf16.
// W[j][n] = sum_k r[k][j]*l[k][n] / N + noise[j][n]
// WF[g][s][lane][i] = W[16g + (lane&15)][32s + (lane>>4)*8 + i]
__global__ void __launch_bounds__(64) build_wf(
    const float* __restrict__ lv,     // [R][N]
    const float* __restrict__ rv,     // [R][N]
    const float* __restrict__ noise,  // [N][N]
    unsigned short* __restrict__ wf)
{
    int blk = blockIdx.x;          // g*32 + s
    int l = threadIdx.x;           // 0..63
    int g = blk >> 5;
    int s = blk & 31;
    int j = g * 16 + (l & 15);
    int n0 = s * 32 + (l >> 4) * 8;
    unsigned short* dst = wf + ((size_t)blk * 64 + l) * 8;
    float rj[R_DIM];
#pragma unroll
    for (int k = 0; k < R_DIM; ++k) rj[k] = rv[k * N_DIM + j];
#pragma unroll
    for (int i = 0; i < 8; ++i) {
        int n = n0 + i;
        float acc = noise[j * N_DIM + n];
        float dot = 0.f;
#pragma unroll
        for (int k = 0; k < R_DIM; ++k) dot += rj[k] * lv[k * N_DIM + n];
        acc += dot * (1.0f / (float)N_DIM);
        dst[i] = f2bf(acc);
    }
}

// Cooperative recurrence kernel.
// 64 blocks x 256 threads. Block g owns j-columns [16g, 16g+16) for all 64 batches.
// Wave w (0..3) handles batch tile rows [16w, 16w+16).
// h-state lives in registers (4 f32 per lane per wave) for all T steps.
__global__ void __launch_bounds__(256) rnn_recurrence(
    const float* __restrict__ hidden0,      // [N]
    const float* __restrict__ input,        // [B][T][N]
    const unsigned short* __restrict__ wf,  // frag layout, 64*32*64*8
    float* __restrict__ out_hidden,         // [T][B][N]
    unsigned short* __restrict__ abuf0,     // [B][N] bf16
    unsigned short* __restrict__ abuf1)     // [B][N] bf16
{
    cg::grid_group grid = cg::this_grid();
    const int g = blockIdx.x;                 // j-tile
    const int w = threadIdx.x >> 6;           // wave -> M tile
    const int l = threadIdx.x & 63;           // lane
    const int jcol = g * 16 + (l & 15);
    const int brow0 = w * 16 + (l >> 4) * 4;  // C/D row base for this lane

    // init h-state: h0[b][n] = hidden0[n] for all b
    float h0v = hidden0[jcol];
    float h[4];
#pragma unroll
    for (int i = 0; i < 4; ++i) h[i] = h0v;

    // init a0 = tanh(h0) into abuf0 (this block's column slice, this wave's rows)
    unsigned short a0 = f2bf(tanhf(h0v));
#pragma unroll
    for (int i = 0; i < 4; ++i) abuf0[(brow0 + i) * N_DIM + jcol] = a0;

    grid.sync();

    // A-fragment base: row = w*16 + (l&15), k-offset (l>>4)*8
    const int arow = w * 16 + (l & 15);
    const int aoff_us = arow * N_DIM + (l >> 4) * 8;   // ushort offset, 16B aligned
    const bf16x8* bfrag_base = reinterpret_cast<const bf16x8*>(wf) + (size_t)g * 32 * 64 + l;

    for (int t = 0; t < T_DIM; ++t) {
        const unsigned short* acur = (t & 1) ? abuf1 : abuf0;
        unsigned short* anext = (t & 1) ? abuf0 : abuf1;

        const bf16x8* afrag = reinterpret_cast<const bf16x8*>(acur + aoff_us);

        f32x4 acc = {0.f, 0.f, 0.f, 0.f};
#pragma unroll 8
        for (int s = 0; s < 32; ++s) {
            bf16x8 av = afrag[s * 4];      // advance 32 bf16 along K per step
            bf16x8 bv = bfrag_base[s * 64];
            acc = __builtin_amdgcn_mfma_f32_16x16x32_bf16(av, bv, acc, 0, 0, 0);
        }

        // epilogue: h = 0.9h + 0.1*(acc + x_t); a = tanh(h); write outputs
#pragma unroll
        for (int i = 0; i < 4; ++i) {
            int b = brow0 + i;
            float x = input[((size_t)b * T_DIM + t) * N_DIM + jcol];
            float hn = 0.9f * h[i] + 0.1f * (acc[i] + x);
            h[i] = hn;
            float a = tanhf(hn);
            out_hidden[((size_t)t * B_DIM + b) * N_DIM + jcol] = a;
            anext[b * N_DIM + jcol] = f2bf(a);
        }

        grid.sync();
    }
}

// geometry = tanh(hidden_t) @ geom_W.T + geom_b ; readout = geometry @ read_W.T
// one wave per (t,b) row
__global__ void __launch_bounds__(256) geo_kernel(
    const float* __restrict__ hid,   // [T*B][N]
    const float* __restrict__ gW,    // [2][N]
    const float* __restrict__ gb,    // [2]
    const float* __restrict__ rW,    // [6][2]
    float* __restrict__ geo,         // [T*B][2]
    float* __restrict__ ro)          // [T*B][6]
{
    int row = blockIdx.x * 4 + (threadIdx.x >> 6);
    int l = threadIdx.x & 63;
    const float* hrow = hid + (size_t)row * N_DIM;
    float a0 = 0.f, a1 = 0.f;
#pragma unroll
    for (int i = 0; i < N_DIM / 64; ++i) {
        int idx = i * 64 + l;
        float th = tanhf(hrow[idx]);
        a0 += th * gW[idx];
        a1 += th * gW[N_DIM + idx];
    }
#pragma unroll
    for (int off = 32; off; off >>= 1) {
        a0 += __shfl_down(a0, off);
        a1 += __shfl_down(a1, off);
    }
    if (l == 0) {
        float g0 = a0 + gb[0];
        float g1 = a1 + gb[1];
        geo[(size_t)row * 2 + 0] = g0;
        geo[(size_t)row * 2 + 1] = g1;
#pragma unroll
        for (int m = 0; m < 6; ++m)
            ro[(size_t)row * 6 + m] = g0 * rW[m * 2] + g1 * rW[m * 2 + 1];
    }
}

extern "C" void kernel_launch(void* const* d_in, const int* in_sizes, int n_in,
                              void* d_out, int out_size, void* d_ws, size_t ws_size,
                              hipStream_t stream) {
    const float* hidden0 = (const float*)d_in[0];
    const float* input   = (const float*)d_in[1];
    const float* lv      = (const float*)d_in[2];
    const float* rv      = (const float*)d_in[3];
    const float* noise   = (const float*)d_in[4];
    const float* gW      = (const float*)d_in[5];
    const float* gb      = (const float*)d_in[6];
    const float* rW      = (const float*)d_in[7];

    float* out_hidden = (float*)d_out;                                  // [T][B][N]
    float* geo = out_hidden + (size_t)T_DIM * B_DIM * N_DIM;            // [T][B][2]
    float* ro  = geo + (size_t)T_DIM * B_DIM * 2;                       // [T][B][6]

    unsigned short* wf    = (unsigned short*)d_ws;                      // 2 MB
    unsigned short* abuf0 = wf + (size_t)64 * 32 * 64 * 8;              // 128 KB
    unsigned short* abuf1 = abuf0 + (size_t)B_DIM * N_DIM;              // 128 KB

    build_wf<<<2048, 64, 0, stream>>>(lv, rv, noise, wf);

    void* args[] = { (void*)&hidden0, (void*)&input, (void*)&wf,
                     (void*)&out_hidden, (void*)&abuf0, (void*)&abuf1 };
    hipLaunchCooperativeKernel((const void*)rnn_recurrence, dim3(64), dim3(256),
                               args, 0, stream);

    geo_kernel<<<(T_DIM * B_DIM) / 4, 256, 0, stream>>>(out_hidden, gW, gb, rW, geo, ro);
}

// Round 2
// 6069.822 us; speedup vs baseline: 1.1091x; 1.1091x over previous
//
#include <hip/hip_runtime.h>
#include <hip/hip_bf16.h>
#include <hip/hip_cooperative_groups.h>

#define N_DIM 1024
#define R_DIM 6
#define B_DIM 64
#define T_DIM 400

typedef short bf16x8 __attribute__((ext_vector_type(8)));
typedef float f32x4 __attribute__((ext_vector_type(4)));

__device__ inline unsigned short f2bf(float f) {
    unsigned int u = __float_as_uint(f);
    unsigned int r = (u + 0x7fffu + ((u >> 16) & 1u)) >> 16;
    return (unsigned short)r;
}

// Build W in MFMA B-fragment layout, bf16.
// WF[g][s][lane][i] = W[16g + (lane&15)][32s + (lane>>4)*8 + i]
// Also zeroes the grid-barrier counter (deterministic per launch).
__global__ void __launch_bounds__(64) build_wf(
    const float* __restrict__ lv,
    const float* __restrict__ rv,
    const float* __restrict__ noise,
    unsigned short* __restrict__ wf,
    unsigned* __restrict__ ctr)
{
    int blk = blockIdx.x;
    int l = threadIdx.x;
    if (blk == 0 && l == 0) *ctr = 0u;   // reset barrier counter every call
    int g = blk >> 5;
    int s = blk & 31;
    int j = g * 16 + (l & 15);
    int n0 = s * 32 + (l >> 4) * 8;
    unsigned short* dst = wf + ((size_t)blk * 64 + l) * 8;
    float rj[R_DIM];
#pragma unroll
    for (int k = 0; k < R_DIM; ++k) rj[k] = rv[k * N_DIM + j];
#pragma unroll
    for (int i = 0; i < 8; ++i) {
        int n = n0 + i;
        float acc = noise[j * N_DIM + n];
        float dot = 0.f;
#pragma unroll
        for (int k = 0; k < R_DIM; ++k) dot += rj[k] * lv[k * N_DIM + n];
        acc += dot * (1.0f / (float)N_DIM);
        dst[i] = f2bf(acc);
    }
}

// Lightweight all-block barrier: release fence + leader atomic arrive,
// leader spin to target, block broadcast. Counter is monotone per launch.
__device__ inline void grid_barrier(unsigned* ctr, unsigned target) {
    __threadfence();            // release: abuf writes visible at device scope
    __syncthreads();            // all waves of block arrived + fenced
    if (threadIdx.x == 0) {
        __hip_atomic_fetch_add(ctr, 1u, __ATOMIC_RELEASE, __HIP_MEMORY_SCOPE_AGENT);
        while (__hip_atomic_load(ctr, __ATOMIC_ACQUIRE, __HIP_MEMORY_SCOPE_AGENT) < target) {
            __builtin_amdgcn_s_sleep(1);
        }
    }
    __syncthreads();            // broadcast leader's acquire to the block
}

// 64 blocks x 256 threads (cooperative). Block g owns j-cols [16g,16g+16)
// for all 64 batches. W fragments live in registers for the whole T-loop.
__global__ void __launch_bounds__(256, 1) rnn_recurrence(
    const float* __restrict__ hidden0,
    const float* __restrict__ input,        // [B][T][N]
    const unsigned short* __restrict__ wf,
    float* __restrict__ out_hidden,         // [T][B][N]
    unsigned short* __restrict__ abuf0,
    unsigned short* __restrict__ abuf1,
    unsigned* __restrict__ ctr)
{
    const int g = blockIdx.x;
    const int w = threadIdx.x >> 6;
    const int l = threadIdx.x & 63;
    const int jcol = g * 16 + (l & 15);
    const int brow0 = w * 16 + (l >> 4) * 4;

    // ---- load this block's W slice into registers: 32 x bf16x8 = 128 VGPR ----
    const bf16x8* bfrag_base = reinterpret_cast<const bf16x8*>(wf) + (size_t)g * 32 * 64 + l;
    bf16x8 wreg[32];
#pragma unroll
    for (int s = 0; s < 32; ++s) wreg[s] = bfrag_base[s * 64];

    // ---- init h-state & publish a0 ----
    float h0v = hidden0[jcol];
    float h[4];
#pragma unroll
    for (int i = 0; i < 4; ++i) h[i] = h0v;
    unsigned short a0 = f2bf(tanhf(h0v));
#pragma unroll
    for (int i = 0; i < 4; ++i) abuf0[(brow0 + i) * N_DIM + jcol] = a0;

    unsigned target = 64;
    grid_barrier(ctr, target);

    const int arow = w * 16 + (l & 15);
    const int aoff_us = arow * N_DIM + (l >> 4) * 8;

    // prefetch x for t=0
    float x[4];
#pragma unroll
    for (int i = 0; i < 4; ++i)
        x[i] = input[((size_t)(brow0 + i) * T_DIM + 0) * N_DIM + jcol];

    for (int t = 0; t < T_DIM; ++t) {
        const unsigned short* acur = (t & 1) ? abuf1 : abuf0;
        unsigned short* anext = (t & 1) ? abuf0 : abuf1;
        const bf16x8* afrag = reinterpret_cast<const bf16x8*>(acur + aoff_us);

        f32x4 acc0 = {0.f, 0.f, 0.f, 0.f};
        f32x4 acc1 = {0.f, 0.f, 0.f, 0.f};
        bf16x8 av[16];

        // first half: stage 16 a-fragments, MFMA through them
#pragma unroll
        for (int s = 0; s < 16; ++s) av[s] = afrag[s * 4];

        // overlap: prefetch x_{t+1} while MFMAs run
        float xn[4];
        if (t + 1 < T_DIM) {
#pragma unroll
            for (int i = 0; i < 4; ++i)
                xn[i] = input[((size_t)(brow0 + i) * T_DIM + (t + 1)) * N_DIM + jcol];
        }

#pragma unroll
        for (int s = 0; s < 16; s += 2) {
            acc0 = __builtin_amdgcn_mfma_f32_16x16x32_bf16(av[s],     wreg[s],     acc0, 0, 0, 0);
            acc1 = __builtin_amdgcn_mfma_f32_16x16x32_bf16(av[s + 1], wreg[s + 1], acc1, 0, 0, 0);
        }

        // second half
#pragma unroll
        for (int s = 0; s < 16; ++s) av[s] = afrag[(16 + s) * 4];
#pragma unroll
        for (int s = 0; s < 16; s += 2) {
            acc0 = __builtin_amdgcn_mfma_f32_16x16x32_bf16(av[s],     wreg[16 + s],     acc0, 0, 0, 0);
            acc1 = __builtin_amdgcn_mfma_f32_16x16x32_bf16(av[s + 1], wreg[16 + s + 1], acc1, 0, 0, 0);
        }

        f32x4 acc = acc0 + acc1;

        // epilogue
#pragma unroll
        for (int i = 0; i < 4; ++i) {
            int b = brow0 + i;
            float hn = 0.9f * h[i] + 0.1f * (acc[i] + x[i]);
            h[i] = hn;
            float a = tanhf(hn);
            out_hidden[((size_t)t * B_DIM + b) * N_DIM + jcol] = a;
            anext[b * N_DIM + jcol] = f2bf(a);
        }
#pragma unroll
        for (int i = 0; i < 4; ++i) x[i] = xn[i];

        target += 64;
        grid_barrier(ctr, target);
    }
}

__global__ void __launch_bounds__(256) geo_kernel(
    const float* __restrict__ hid,
    const float* __restrict__ gW,
    const float* __restrict__ gb,
    const float* __restrict__ rW,
    float* __restrict__ geo,
    float* __restrict__ ro)
{
    int row = blockIdx.x * 4 + (threadIdx.x >> 6);
    int l = threadIdx.x & 63;
    const float* hrow = hid + (size_t)row * N_DIM;
    float a0 = 0.f, a1 = 0.f;
#pragma unroll
    for (int i = 0; i < N_DIM / 64; ++i) {
        int idx = i * 64 + l;
        float th = tanhf(hrow[idx]);
        a0 += th * gW[idx];
        a1 += th * gW[N_DIM + idx];
    }
#pragma unroll
    for (int off = 32; off; off >>= 1) {
        a0 += __shfl_down(a0, off);
        a1 += __shfl_down(a1, off);
    }
    if (l == 0) {
        float g0 = a0 + gb[0];
        float g1 = a1 + gb[1];
        geo[(size_t)row * 2 + 0] = g0;
        geo[(size_t)row * 2 + 1] = g1;
#pragma unroll
        for (int m = 0; m < 6; ++m)
            ro[(size_t)row * 6 + m] = g0 * rW[m * 2] + g1 * rW[m * 2 + 1];
    }
}

extern "C" void kernel_launch(void* const* d_in, const int* in_sizes, int n_in,
                              void* d_out, int out_size, void* d_ws, size_t ws_size,
                              hipStream_t stream) {
    const float* hidden0 = (const float*)d_in[0];
    const float* input   = (const float*)d_in[1];
    const float* lv      = (const float*)d_in[2];
    const float* rv      = (const float*)d_in[3];
    const float* noise   = (const float*)d_in[4];
    const float* gW      = (const float*)d_in[5];
    const float* gb      = (const float*)d_in[6];
    const float* rW      = (const float*)d_in[7];

    float* out_hidden = (float*)d_out;
    float* geo = out_hidden + (size_t)T_DIM * B_DIM * N_DIM;
    float* ro  = geo + (size_t)T_DIM * B_DIM * 2;

    unsigned short* wf    = (unsigned short*)d_ws;                 // 2 MB
    unsigned short* abuf0 = wf + (size_t)64 * 32 * 64 * 8;         // 128 KB
    unsigned short* abuf1 = abuf0 + (size_t)B_DIM * N_DIM;         // 128 KB
    unsigned* ctr = (unsigned*)(abuf1 + (size_t)B_DIM * N_DIM);    // 4 B

    build_wf<<<2048, 64, 0, stream>>>(lv, rv, noise, wf, ctr);

    void* args[] = { (void*)&hidden0, (void*)&input, (void*)&wf,
                     (void*)&out_hidden, (void*)&abuf0, (void*)&abuf1, (void*)&ctr };
    hipLaunchCooperativeKernel((const void*)rnn_recurrence, dim3(64), dim3(256),
                               args, 0, stream);

    geo_kernel<<<(T_DIM * B_DIM) / 4, 256, 0, stream>>>(out_hidden, gW, gb, rW, geo, ro);
}